// Round 4
// baseline (909.320 us; speedup 1.0000x reference)
//
#include <hip/hip_runtime.h>
#include <math.h>

#define NLEVELS 16
#define LOG2_T 19
#define TSIZE (1u << LOG2_T)
#define TMASK (TSIZE - 1u)
#define NPTS 1048576
#define P2 2654435761u
#define P3 805459861u

typedef float vfloat2 __attribute__((ext_vector_type(2)));

struct Res16 { float r[NLEVELS]; };

// 2D grid: blockIdx.y = level (temporal phasing keeps the active 4 MiB level
// slice L2-resident per XCD — verified R3: FETCH_SIZE ~= compulsory).
// 2 points per thread: 16 gathers in flight per wave instead of 8 -> ~2x
// memory-level parallelism per CU (R3 showed we're latency/MLP-bound at
// 0.29 lane-req/cyc/CU, not bandwidth-bound).
__global__ __launch_bounds__(256) void HashGridEncoder_68925635166659_kernel(
    const float* __restrict__ x,
    const vfloat2* __restrict__ table,
    vfloat2* __restrict__ out,
    Res16 res)
{
    const int l = blockIdx.y;
    const int t = blockIdx.x * blockDim.x + threadIdx.x;
    const int n0 = 2 * t;            // points n0, n0+1

    // 6 contiguous floats for both points, 3x dwordx2 (8B-aligned), one batch.
    const vfloat2* __restrict__ xv = (const vfloat2*)x;
    const vfloat2 xa = __builtin_nontemporal_load(xv + 3 * t + 0); // px0 py0
    const vfloat2 xb = __builtin_nontemporal_load(xv + 3 * t + 1); // pz0 px1
    const vfloat2 xc = __builtin_nontemporal_load(xv + 3 * t + 2); // py1 pz1

    const float r = res.r[l];
    const vfloat2* __restrict__ tl = table + (uint32_t)l * TSIZE;

    // ---- point 0 address math ----
    const float sx0 = xa.x * r, sy0 = xa.y * r, sz0 = xb.x * r;
    const float fx0 = floorf(sx0), fy0 = floorf(sy0), fz0 = floorf(sz0);
    const float wxA = sx0 - fx0, wyA = sy0 - fy0, wzA = sz0 - fz0;
    const uint32_t ixA = (uint32_t)(int)fx0;
    const uint32_t iyA = (uint32_t)(int)fy0;
    const uint32_t izA = (uint32_t)(int)fz0;
    const uint32_t Ax0 = ixA,            Ax1 = ixA + 1u;
    const uint32_t Ay0 = iyA * P2,       Ay1 = Ay0 + P2;
    const uint32_t Az0 = izA * P3,       Az1 = Az0 + P3;

    // ---- point 1 address math ----
    const float sx1 = xb.y * r, sy1 = xc.x * r, sz1 = xc.y * r;
    const float fx1 = floorf(sx1), fy1 = floorf(sy1), fz1 = floorf(sz1);
    const float wxB = sx1 - fx1, wyB = sy1 - fy1, wzB = sz1 - fz1;
    const uint32_t ixB = (uint32_t)(int)fx1;
    const uint32_t iyB = (uint32_t)(int)fy1;
    const uint32_t izB = (uint32_t)(int)fz1;
    const uint32_t Bx0 = ixB,            Bx1 = ixB + 1u;
    const uint32_t By0 = iyB * P2,       By1 = By0 + P2;
    const uint32_t Bz0 = izB * P3,       Bz1 = Bz0 + P3;

    // ---- 16 independent gathers, all issued before any use ----
    const vfloat2 a000 = tl[(Ax0 ^ Ay0 ^ Az0) & TMASK];
    const vfloat2 a001 = tl[(Ax0 ^ Ay0 ^ Az1) & TMASK];
    const vfloat2 a010 = tl[(Ax0 ^ Ay1 ^ Az0) & TMASK];
    const vfloat2 a011 = tl[(Ax0 ^ Ay1 ^ Az1) & TMASK];
    const vfloat2 a100 = tl[(Ax1 ^ Ay0 ^ Az0) & TMASK];
    const vfloat2 a101 = tl[(Ax1 ^ Ay0 ^ Az1) & TMASK];
    const vfloat2 a110 = tl[(Ax1 ^ Ay1 ^ Az0) & TMASK];
    const vfloat2 a111 = tl[(Ax1 ^ Ay1 ^ Az1) & TMASK];
    const vfloat2 b000 = tl[(Bx0 ^ By0 ^ Bz0) & TMASK];
    const vfloat2 b001 = tl[(Bx0 ^ By0 ^ Bz1) & TMASK];
    const vfloat2 b010 = tl[(Bx0 ^ By1 ^ Bz0) & TMASK];
    const vfloat2 b011 = tl[(Bx0 ^ By1 ^ Bz1) & TMASK];
    const vfloat2 b100 = tl[(Bx1 ^ By0 ^ Bz0) & TMASK];
    const vfloat2 b101 = tl[(Bx1 ^ By0 ^ Bz1) & TMASK];
    const vfloat2 b110 = tl[(Bx1 ^ By1 ^ Bz0) & TMASK];
    const vfloat2 b111 = tl[(Bx1 ^ By1 ^ Bz1) & TMASK];

    // ---- point 0 interpolation (reference corner order, dz innermost) ----
    {
        const float wx0 = 1.0f - wxA, wy0 = 1.0f - wyA, wz0 = 1.0f - wzA;
        float f0 = 0.0f, f1 = 0.0f, w;
        w = (wx0 * wy0) * wz0; f0 += a000.x * w; f1 += a000.y * w;
        w = (wx0 * wy0) * wzA; f0 += a001.x * w; f1 += a001.y * w;
        w = (wx0 * wyA) * wz0; f0 += a010.x * w; f1 += a010.y * w;
        w = (wx0 * wyA) * wzA; f0 += a011.x * w; f1 += a011.y * w;
        w = (wxA * wy0) * wz0; f0 += a100.x * w; f1 += a100.y * w;
        w = (wxA * wy0) * wzA; f0 += a101.x * w; f1 += a101.y * w;
        w = (wxA * wyA) * wz0; f0 += a110.x * w; f1 += a110.y * w;
        w = (wxA * wyA) * wzA; f0 += a111.x * w; f1 += a111.y * w;
        vfloat2 v; v.x = f0; v.y = f1;
        __builtin_nontemporal_store(v, out + (uint32_t)n0 * NLEVELS + (uint32_t)l);
    }

    // ---- point 1 interpolation ----
    {
        const float wx0 = 1.0f - wxB, wy0 = 1.0f - wyB, wz0 = 1.0f - wzB;
        float f0 = 0.0f, f1 = 0.0f, w;
        w = (wx0 * wy0) * wz0; f0 += b000.x * w; f1 += b000.y * w;
        w = (wx0 * wy0) * wzB; f0 += b001.x * w; f1 += b001.y * w;
        w = (wx0 * wyB) * wz0; f0 += b010.x * w; f1 += b010.y * w;
        w = (wx0 * wyB) * wzB; f0 += b011.x * w; f1 += b011.y * w;
        w = (wxB * wy0) * wz0; f0 += b100.x * w; f1 += b100.y * w;
        w = (wxB * wy0) * wzB; f0 += b101.x * w; f1 += b101.y * w;
        w = (wxB * wyB) * wz0; f0 += b110.x * w; f1 += b110.y * w;
        w = (wxB * wyB) * wzB; f0 += b111.x * w; f1 += b111.y * w;
        vfloat2 v; v.x = f0; v.y = f1;
        __builtin_nontemporal_store(v, out + (uint32_t)(n0 + 1) * NLEVELS + (uint32_t)l);
    }
}

extern "C" void kernel_launch(void* const* d_in, const int* in_sizes, int n_in,
                              void* d_out, int out_size, void* d_ws, size_t ws_size,
                              hipStream_t stream) {
    const float*   x     = (const float*)d_in[0];
    const vfloat2* table = (const vfloat2*)d_in[1];
    vfloat2*       out   = (vfloat2*)d_out;

    // Exact numpy recipe in double: floor(16 * growth^l), growth = exp(ln(256)/15)
    Res16 res;
    const double growth = exp((log(4096.0) - log(16.0)) / 15.0);
    for (int l = 0; l < NLEVELS; ++l)
        res.r[l] = (float)floor(16.0 * pow(growth, (double)l));

    const dim3 block(256, 1, 1);
    const dim3 grid(NPTS / 2 / 256, NLEVELS, 1);   // 2048 x 16

    HashGridEncoder_68925635166659_kernel<<<grid, block, 0, stream>>>(x, table, out, res);
}